// Round 1
// baseline (2417.178 us; speedup 1.0000x reference)
//
#include <hip/hip_runtime.h>

#define DIM 64
#define PRESERVE 0.1f

// deg init to self-loop weight 1.0
__global__ void k_init_deg(float* deg, int n) {
    int i = blockIdx.x * blockDim.x + threadIdx.x;
    if (i < n) deg[i] = 1.0f;
}

// deg[col[e]] += w[e]
__global__ void k_deg(const int* __restrict__ col, const float* __restrict__ w,
                      float* deg, int E) {
    int e = blockIdx.x * blockDim.x + threadIdx.x;
    if (e < E) atomicAdd(&deg[col[e]], w[e]);
}

// in-place deg -> rsqrt(deg)
__global__ void k_dinv(float* deg, int n) {
    int i = blockIdx.x * blockDim.x + threadIdx.x;
    if (i < n) {
        float d = deg[i];
        deg[i] = (d > 0.0f) ? rsqrtf(d) : 0.0f;
    }
}

// norm[e] = dinv[row]*w*dinv[col]
__global__ void k_norm(const int* __restrict__ row, const int* __restrict__ col,
                       const float* __restrict__ w, const float* __restrict__ dinv,
                       float* __restrict__ norm, int E) {
    int e = blockIdx.x * blockDim.x + threadIdx.x;
    if (e < E) norm[e] = dinv[row[e]] * w[e] * dinv[col[e]];
}

// xw = x @ W ; acc = xw * dinv^2  (self-loop message, initializes accumulator)
// one wave per row, 4 rows per block of 256
__global__ __launch_bounds__(256) void k_mm(
        const float* __restrict__ x, const float* __restrict__ W,
        const float* __restrict__ dinv, float* __restrict__ xw,
        float* __restrict__ acc, int n) {
    __shared__ float Wl[DIM * DIM];
    __shared__ float xl[4 * DIM];
    int tid = threadIdx.x;
    for (int i = tid; i < DIM * DIM; i += 256) Wl[i] = W[i];
    int rowBase = blockIdx.x * 4;
    if (rowBase + (tid >> 6) < n) xl[tid] = x[rowBase * DIM + tid];
    __syncthreads();
    int sub = tid >> 6;
    int d = tid & 63;
    int r = rowBase + sub;
    if (r >= n) return;
    float t = 0.0f;
#pragma unroll
    for (int k = 0; k < DIM; ++k) t += xl[sub * DIM + k] * Wl[k * DIM + d];
    float di = dinv[r];
    xw[(size_t)r * DIM + d] = t;
    acc[(size_t)r * DIM + d] = t * di * di;
}

// acc[col] += xw[row] * norm ; 16 lanes per edge, float4 per lane
__global__ __launch_bounds__(256) void k_scatter(
        const float4* __restrict__ xw4, const float* __restrict__ norm,
        const int* __restrict__ row, const int* __restrict__ col,
        float* __restrict__ acc, int E) {
    int t = blockIdx.x * blockDim.x + threadIdx.x;
    int e = t >> 4;
    int sub = t & 15;
    if (e >= E) return;
    int r = row[e];
    int c = col[e];
    float nm = norm[e];
    float4 v = xw4[(size_t)r * 16 + sub];
    float* a = acc + (size_t)c * DIM + sub * 4;
    atomicAdd(a + 0, v.x * nm);
    atomicAdd(a + 1, v.y * nm);
    atomicAdd(a + 2, v.z * nm);
    atomicAdd(a + 3, v.w * nm);
}

// out = 0.9*(acc + b) + 0.1*xprev   (float4-vectorized; safe in-place acc==out)
__global__ void k_final(const float* __restrict__ acc, const float* __restrict__ b,
                        const float* __restrict__ xprev, float* __restrict__ out,
                        int total4) {
    int i = blockIdx.x * blockDim.x + threadIdx.x;
    if (i >= total4) return;
    float4 a = ((const float4*)acc)[i];
    float4 xp = ((const float4*)xprev)[i];
    float4 bb = ((const float4*)b)[i & 15];  // (4i % 64) / 4
    float4 o;
    o.x = (1.0f - PRESERVE) * (a.x + bb.x) + PRESERVE * xp.x;
    o.y = (1.0f - PRESERVE) * (a.y + bb.y) + PRESERVE * xp.y;
    o.z = (1.0f - PRESERVE) * (a.z + bb.z) + PRESERVE * xp.z;
    o.w = (1.0f - PRESERVE) * (a.w + bb.w) + PRESERVE * xp.w;
    ((float4*)out)[i] = o;
}

extern "C" void kernel_launch(void* const* d_in, const int* in_sizes, int n_in,
                              void* d_out, int out_size, void* d_ws, size_t ws_size,
                              hipStream_t stream) {
    const float* x  = (const float*)d_in[0];
    const int*   ei = (const int*)d_in[1];
    const float* ew = (const float*)d_in[2];
    const float* W1 = (const float*)d_in[3];
    const float* b1 = (const float*)d_in[4];
    const float* W2 = (const float*)d_in[5];
    const float* b2 = (const float*)d_in[6];

    const int N = in_sizes[0] / DIM;      // 100000
    const int E = in_sizes[2];            // 1250000
    const int* row = ei;
    const int* col = ei + E;

    float* ws   = (float*)d_ws;
    float* dinv = ws;                         // N   (deg, then rsqrt in-place)
    float* norm = dinv + N;                   // E
    float* xw   = norm + E;                   // N*64
    float* temp = xw + (size_t)N * DIM;       // N*64
    float* acc  = (float*)d_out;              // N*64 accumulator (reused both layers)
    float* out  = (float*)d_out;

    const int B = 256;
    const int total4 = N * DIM / 4;

    // normalization (shared by both layers)
    k_init_deg<<<(N + B - 1) / B, B, 0, stream>>>(dinv, N);
    k_deg<<<(E + B - 1) / B, B, 0, stream>>>(col, ew, dinv, E);
    k_dinv<<<(N + B - 1) / B, B, 0, stream>>>(dinv, N);
    k_norm<<<(E + B - 1) / B, B, 0, stream>>>(row, col, ew, dinv, norm, E);

    // layer 1
    k_mm<<<(N + 3) / 4, B, 0, stream>>>(x, W1, dinv, xw, acc, N);
    {
        long long th = (long long)E * 16;
        k_scatter<<<(int)((th + B - 1) / B), B, 0, stream>>>(
            (const float4*)xw, norm, row, col, acc, E);
    }
    k_final<<<(total4 + B - 1) / B, B, 0, stream>>>(acc, b1, x, temp, total4);

    // layer 2
    k_mm<<<(N + 3) / 4, B, 0, stream>>>(temp, W2, dinv, xw, acc, N);
    {
        long long th = (long long)E * 16;
        k_scatter<<<(int)((th + B - 1) / B), B, 0, stream>>>(
            (const float4*)xw, norm, row, col, acc, E);
    }
    k_final<<<(total4 + B - 1) / B, B, 0, stream>>>(acc, b2, temp, out, total4);
}

// Round 2
// 549.119 us; speedup vs baseline: 4.4019x; 4.4019x over previous
//
#include <hip/hip_runtime.h>

#define DIM 64
#define PRESERVE 0.1f

// ---------- normalization + CSR histogram ----------

// deg init to self-loop weight 1.0 ; counts init 0
__global__ void k_init(float* deg, int* counts, int n) {
    int i = blockIdx.x * blockDim.x + threadIdx.x;
    if (i < n) { deg[i] = 1.0f; counts[i] = 0; }
}

// one pass over edges: deg[col] += w ; counts[col] += 1
__global__ void k_edge_pre(const int* __restrict__ col, const float* __restrict__ w,
                           float* deg, int* counts, int E) {
    int e = blockIdx.x * blockDim.x + threadIdx.x;
    if (e < E) {
        int c = col[e];
        atomicAdd(&deg[c], w[e]);
        atomicAdd(&counts[c], 1);
    }
}

// in-place deg -> rsqrt(deg)
__global__ void k_dinv(float* deg, int n) {
    int i = blockIdx.x * blockDim.x + threadIdx.x;
    if (i < n) {
        float d = deg[i];
        deg[i] = (d > 0.0f) ? rsqrtf(d) : 0.0f;
    }
}

// ---------- 2-level exclusive scan of counts -> offsets ----------

// per-block inclusive scan of counts into offsets (raw), block total -> blksum
__global__ __launch_bounds__(256) void k_scan1(const int* __restrict__ counts,
                                               int* __restrict__ offsets,
                                               int* __restrict__ blksum, int n) {
    __shared__ int s[256];
    int t = threadIdx.x;
    int idx = blockIdx.x * 256 + t;
    int v = (idx < n) ? counts[idx] : 0;
    s[t] = v;
    __syncthreads();
    for (int off = 1; off < 256; off <<= 1) {
        int x = (t >= off) ? s[t - off] : 0;
        __syncthreads();
        s[t] += x;
        __syncthreads();
    }
    if (idx < n) offsets[idx] = s[t];
    if (t == 255) blksum[blockIdx.x] = s[255];
}

// single block: exclusive scan of blksum -> blkoff (nblk <= 512)
__global__ __launch_bounds__(512) void k_scan2(const int* __restrict__ blksum,
                                               int* __restrict__ blkoff, int nblk) {
    __shared__ int s[512];
    int t = threadIdx.x;
    int v = (t < nblk) ? blksum[t] : 0;
    s[t] = v;
    __syncthreads();
    for (int off = 1; off < 512; off <<= 1) {
        int x = (t >= off) ? s[t - off] : 0;
        __syncthreads();
        s[t] += x;
        __syncthreads();
    }
    if (t < nblk) blkoff[t] = s[t] - v;  // exclusive
}

// offsets[idx] := exclusive global offset ; cursor := copy ; offsets[n] = E
__global__ __launch_bounds__(256) void k_scan3(const int* __restrict__ counts,
                                               int* __restrict__ offsets,
                                               int* __restrict__ cursor,
                                               const int* __restrict__ blkoff,
                                               int n, int E) {
    int t = threadIdx.x;
    int idx = blockIdx.x * 256 + t;
    if (idx < n) {
        int excl = offsets[idx] - counts[idx] + blkoff[blockIdx.x];
        offsets[idx] = excl;
        cursor[idx] = excl;
    }
    if (idx == 0) offsets[n] = E;
}

// bucket-fill CSR: sedge[pos] = {row, norm} for each edge, grouped by col
__global__ void k_fill(const int* __restrict__ row, const int* __restrict__ col,
                       const float* __restrict__ w, const float* __restrict__ dinv,
                       int* cursor, int2* __restrict__ sedge, int E) {
    int e = blockIdx.x * blockDim.x + threadIdx.x;
    if (e >= E) return;
    int c = col[e];
    int r = row[e];
    int pos = atomicAdd(&cursor[c], 1);
    float nm = dinv[r] * w[e] * dinv[c];
    int2 p;
    p.x = r;
    p.y = __float_as_int(nm);
    sedge[pos] = p;
}

// ---------- compute ----------

// xw = x @ W ; one wave per row, 4 rows per block of 256
__global__ __launch_bounds__(256) void k_mm(
        const float* __restrict__ x, const float* __restrict__ W,
        float* __restrict__ xw, int n) {
    __shared__ float Wl[DIM * DIM];
    __shared__ float xl[4 * DIM];
    int tid = threadIdx.x;
    for (int i = tid; i < DIM * DIM; i += 256) Wl[i] = W[i];
    int rowBase = blockIdx.x * 4;
    if (rowBase + (tid >> 6) < n) xl[tid] = x[rowBase * DIM + tid];
    __syncthreads();
    int sub = tid >> 6;
    int d = tid & 63;
    int r = rowBase + sub;
    if (r >= n) return;
    float t = 0.0f;
#pragma unroll
    for (int k = 0; k < DIM; ++k) t += xl[sub * DIM + k] * Wl[k * DIM + d];
    xw[(size_t)r * DIM + d] = t;
}

// gather per target node (one wave per node, lane = output dim):
// out[c] = 0.9*( xw[c]*dinv[c]^2 + sum_in xw[r]*norm + b ) + 0.1*xprev[c]
__global__ __launch_bounds__(256) void k_gather(
        const float* __restrict__ xw, const int* __restrict__ offsets,
        const int2* __restrict__ sedge, const float* __restrict__ dinv,
        const float* __restrict__ b, const float* __restrict__ xprev,
        float* __restrict__ out, int n) {
    int tid = threadIdx.x;
    int wave = tid >> 6;
    int d = tid & 63;
    int c = blockIdx.x * 4 + wave;
    if (c >= n) return;
    float di = dinv[c];
    float acc = xw[(size_t)c * DIM + d] * di * di;  // self-loop message
    int beg = offsets[c];
    int end = offsets[c + 1];
    int j = beg;
    for (; j + 1 < end; j += 2) {
        int2 p0 = sedge[j];
        int2 p1 = sedge[j + 1];
        float a0 = xw[(size_t)p0.x * DIM + d];
        float a1 = xw[(size_t)p1.x * DIM + d];
        acc += a0 * __int_as_float(p0.y);
        acc += a1 * __int_as_float(p1.y);
    }
    if (j < end) {
        int2 p = sedge[j];
        acc += xw[(size_t)p.x * DIM + d] * __int_as_float(p.y);
    }
    float v = (1.0f - PRESERVE) * (acc + b[d]) + PRESERVE * xprev[(size_t)c * DIM + d];
    out[(size_t)c * DIM + d] = v;
}

extern "C" void kernel_launch(void* const* d_in, const int* in_sizes, int n_in,
                              void* d_out, int out_size, void* d_ws, size_t ws_size,
                              hipStream_t stream) {
    const float* x  = (const float*)d_in[0];
    const int*   ei = (const int*)d_in[1];
    const float* ew = (const float*)d_in[2];
    const float* W1 = (const float*)d_in[3];
    const float* b1 = (const float*)d_in[4];
    const float* W2 = (const float*)d_in[5];
    const float* b2 = (const float*)d_in[6];

    const int N = in_sizes[0] / DIM;      // 100000
    const int E = in_sizes[2];            // 1250000
    const int* row = ei;
    const int* col = ei + E;

    // workspace layout
    float* f    = (float*)d_ws;
    float* dinv = f;                              // N
    float* xw   = dinv + N;                       // N*64
    float* temp = xw + (size_t)N * DIM;           // N*64
    int* ip      = (int*)(temp + (size_t)N * DIM);
    int* counts  = ip;                            // N
    int* offsets = counts + N;                    // N+1
    int* cursor  = offsets + N + 1;               // N
    int* blksum  = cursor + N;                    // up to 640
    int* blkoff  = blksum + 640;                  // up to 640
    int2* sedge  = (int2*)((((uintptr_t)(blkoff + 640)) + 7) & ~(uintptr_t)7);  // E

    const int B = 256;
    const int nblkN = (N + B - 1) / B;   // 391 (must be <= 512 for k_scan2)
    const int nblkE = (E + B - 1) / B;
    const int nblkG = (N + 3) / 4;

    // degree + histogram
    k_init<<<nblkN, B, 0, stream>>>(dinv, counts, N);
    k_edge_pre<<<nblkE, B, 0, stream>>>(col, ew, dinv, counts, E);
    k_dinv<<<nblkN, B, 0, stream>>>(dinv, N);

    // CSR build
    k_scan1<<<nblkN, B, 0, stream>>>(counts, offsets, blksum, N);
    k_scan2<<<1, 512, 0, stream>>>(blksum, blkoff, nblkN);
    k_scan3<<<nblkN, B, 0, stream>>>(counts, offsets, cursor, blkoff, N, E);
    k_fill<<<nblkE, B, 0, stream>>>(row, col, ew, dinv, cursor, sedge, E);

    // layer 1
    k_mm<<<nblkG, B, 0, stream>>>(x, W1, xw, N);
    k_gather<<<nblkG, B, 0, stream>>>(xw, offsets, sedge, dinv, b1, x, temp, N);

    // layer 2
    k_mm<<<nblkG, B, 0, stream>>>(temp, W2, xw, N);
    k_gather<<<nblkG, B, 0, stream>>>(xw, offsets, sedge, dinv, b2, temp, (float*)d_out, N);
}

// Round 3
// 415.573 us; speedup vs baseline: 5.8165x; 1.3214x over previous
//
#include <hip/hip_runtime.h>

#define DIM 64
#define PRESERVE 0.1f

__device__ __forceinline__ float readlane_f(float v, int l) {
    return __int_as_float(__builtin_amdgcn_readlane(__float_as_int(v), l));
}

// ---------- init ----------
__global__ void k_init(int* cursor, int n) {
    int i = blockIdx.x * blockDim.x + threadIdx.x;
    if (i < n) cursor[i] = 0;
}

// ---------- histogram + rank (atomic return = rank in bucket) ----------
__global__ void k_hist4(const int4* __restrict__ col4, int* cursor,
                        int4* __restrict__ rank4, int nthreads) {
    int t = blockIdx.x * blockDim.x + threadIdx.x;
    if (t >= nthreads) return;
    int4 c = col4[t];
    int4 r;
    r.x = atomicAdd(&cursor[c.x], 1);
    r.y = atomicAdd(&cursor[c.y], 1);
    r.z = atomicAdd(&cursor[c.z], 1);
    r.w = atomicAdd(&cursor[c.w], 1);
    rank4[t] = r;
}

__global__ void k_hist1(const int* __restrict__ col, int* cursor,
                        int* __restrict__ rank, int E) {
    int e = blockIdx.x * blockDim.x + threadIdx.x;
    if (e < E) rank[e] = atomicAdd(&cursor[col[e]], 1);
}

// ---------- 2-level exclusive scan of counts(=cursor) -> offsets ----------
__global__ __launch_bounds__(256) void k_scan1(const int* __restrict__ counts,
                                               int* __restrict__ offsets,
                                               int* __restrict__ blksum, int n) {
    __shared__ int s[256];
    int t = threadIdx.x;
    int idx = blockIdx.x * 256 + t;
    int v = (idx < n) ? counts[idx] : 0;
    s[t] = v;
    __syncthreads();
    for (int off = 1; off < 256; off <<= 1) {
        int x = (t >= off) ? s[t - off] : 0;
        __syncthreads();
        s[t] += x;
        __syncthreads();
    }
    if (idx < n) offsets[idx] = s[t];
    if (t == 255) blksum[blockIdx.x] = s[255];
}

__global__ __launch_bounds__(512) void k_scan2(const int* __restrict__ blksum,
                                               int* __restrict__ blkoff, int nblk) {
    __shared__ int s[512];
    int t = threadIdx.x;
    int v = (t < nblk) ? blksum[t] : 0;
    s[t] = v;
    __syncthreads();
    for (int off = 1; off < 512; off <<= 1) {
        int x = (t >= off) ? s[t - off] : 0;
        __syncthreads();
        s[t] += x;
        __syncthreads();
    }
    if (t < nblk) blkoff[t] = s[t] - v;  // exclusive
}

__global__ __launch_bounds__(256) void k_scan3(const int* __restrict__ counts,
                                               int* __restrict__ offsets,
                                               const int* __restrict__ blkoff,
                                               int n, int E) {
    int t = threadIdx.x;
    int idx = blockIdx.x * 256 + t;
    if (idx < n) offsets[idx] = offsets[idx] - counts[idx] + blkoff[blockIdx.x];
    if (idx == 0) offsets[n] = E;
}

// ---------- bucket-fill CSR: sedge[offsets[col]+rank] = {row, w} ----------
__global__ void k_fill4(const int4* __restrict__ row4, const int4* __restrict__ col4,
                        const float4* __restrict__ w4, const int4* __restrict__ rank4,
                        const int* __restrict__ offsets, int2* __restrict__ sedge,
                        int nthreads) {
    int t = blockIdx.x * blockDim.x + threadIdx.x;
    if (t >= nthreads) return;
    int4 r = row4[t];
    int4 c = col4[t];
    float4 w = w4[t];
    int4 k = rank4[t];
    int2 p;
    p.x = r.x; p.y = __float_as_int(w.x); sedge[offsets[c.x] + k.x] = p;
    p.x = r.y; p.y = __float_as_int(w.y); sedge[offsets[c.y] + k.y] = p;
    p.x = r.z; p.y = __float_as_int(w.z); sedge[offsets[c.z] + k.z] = p;
    p.x = r.w; p.y = __float_as_int(w.w); sedge[offsets[c.w] + k.w] = p;
}

__global__ void k_fill1(const int* __restrict__ row, const int* __restrict__ col,
                        const float* __restrict__ w, const int* __restrict__ rank,
                        const int* __restrict__ offsets, int2* __restrict__ sedge,
                        int E) {
    int e = blockIdx.x * blockDim.x + threadIdx.x;
    if (e >= E) return;
    int2 p;
    p.x = row[e];
    p.y = __float_as_int(w[e]);
    sedge[offsets[col[e]] + rank[e]] = p;
}

// ---------- deg -> dinv from CSR (wave per node, no atomics) ----------
__global__ __launch_bounds__(256) void k_deg_seg(const int2* __restrict__ sedge,
                                                 const int* __restrict__ offsets,
                                                 float* __restrict__ dinv, int n) {
    int tid = threadIdx.x;
    int lane = tid & 63;
    int c = blockIdx.x * 4 + (tid >> 6);
    if (c >= n) return;
    int beg = offsets[c];
    int end = offsets[c + 1];
    float s = 0.0f;
    for (int j = beg + lane; j < end; j += 64) s += __int_as_float(sedge[j].y);
    for (int off = 32; off > 0; off >>= 1) s += __shfl_xor(s, off);
    if (lane == 0) {
        float d = 1.0f + s;  // self-loop weight
        dinv[c] = (d > 0.0f) ? rsqrtf(d) : 0.0f;
    }
}

// ---------- xw = x @ W ----------
__global__ __launch_bounds__(256) void k_mm(
        const float* __restrict__ x, const float* __restrict__ W,
        float* __restrict__ xw, int n) {
    __shared__ float Wl[DIM * DIM];
    __shared__ float xl[4 * DIM];
    int tid = threadIdx.x;
    for (int i = tid; i < DIM * DIM; i += 256) Wl[i] = W[i];
    int rowBase = blockIdx.x * 4;
    if (rowBase + (tid >> 6) < n) xl[tid] = x[rowBase * DIM + tid];
    __syncthreads();
    int sub = tid >> 6;
    int d = tid & 63;
    int r = rowBase + sub;
    if (r >= n) return;
    float t = 0.0f;
#pragma unroll
    for (int k = 0; k < DIM; ++k) t += xl[sub * DIM + k] * Wl[k * DIM + d];
    xw[(size_t)r * DIM + d] = t;
}

// ---------- gather (wave per node, lane = dim) ----------
// out[c] = 0.9*( xw[c]*dinv[c]^2 + sum_in xw[r]*dinv[r]*w*dinv[c] + b ) + 0.1*xprev[c]
__global__ __launch_bounds__(256) void k_gather(
        const float* __restrict__ xw, const int* __restrict__ offsets,
        const int2* __restrict__ sedge, const float* __restrict__ dinv,
        const float* __restrict__ b, const float* __restrict__ xprev,
        float* __restrict__ out, int n) {
    int tid = threadIdx.x;
    int lane = tid & 63;
    int c = blockIdx.x * 4 + (tid >> 6);
    if (c >= n) return;
    float di = dinv[c];
    float acc = xw[(size_t)c * DIM + lane] * di * di;  // self-loop message
    int beg = offsets[c];
    int end = offsets[c + 1];
    for (int b0 = beg; b0 < end; b0 += 64) {
        int m = end - b0;
        if (m > 64) m = 64;
        int r_l = 0;
        float nm_l = 0.0f;
        if (lane < m) {
            int2 p = sedge[b0 + lane];            // coalesced batch load
            r_l = p.x;
            nm_l = dinv[p.x] * __int_as_float(p.y) * di;  // norm on the fly
        }
        int j = 0;
        for (; j + 1 < m; j += 2) {
            int r0 = __builtin_amdgcn_readlane(r_l, j);
            int r1 = __builtin_amdgcn_readlane(r_l, j + 1);
            float nm0 = readlane_f(nm_l, j);
            float nm1 = readlane_f(nm_l, j + 1);
            float a0 = xw[(size_t)r0 * DIM + lane];
            float a1 = xw[(size_t)r1 * DIM + lane];
            acc += a0 * nm0;
            acc += a1 * nm1;
        }
        if (j < m) {
            int r0 = __builtin_amdgcn_readlane(r_l, j);
            float nm0 = readlane_f(nm_l, j);
            acc += xw[(size_t)r0 * DIM + lane] * nm0;
        }
    }
    float v = (1.0f - PRESERVE) * (acc + b[lane]) + PRESERVE * xprev[(size_t)c * DIM + lane];
    out[(size_t)c * DIM + lane] = v;
}

extern "C" void kernel_launch(void* const* d_in, const int* in_sizes, int n_in,
                              void* d_out, int out_size, void* d_ws, size_t ws_size,
                              hipStream_t stream) {
    const float* x  = (const float*)d_in[0];
    const int*   ei = (const int*)d_in[1];
    const float* ew = (const float*)d_in[2];
    const float* W1 = (const float*)d_in[3];
    const float* b1 = (const float*)d_in[4];
    const float* W2 = (const float*)d_in[5];
    const float* b2 = (const float*)d_in[6];

    const int N = in_sizes[0] / DIM;      // 100000
    const int E = in_sizes[2];            // 1250000
    const int* row = ei;
    const int* col = ei + E;

    // workspace layout (sedge first for 8B alignment)
    int2* sedge   = (int2*)d_ws;                          // E
    float* dinv   = (float*)(sedge + E);                  // N
    float* xw     = dinv + N;                             // N*DIM
    float* temp   = xw + (size_t)N * DIM;                 // N*DIM
    int* rank     = (int*)(temp + (size_t)N * DIM);       // E
    int* cursor   = rank + E;                             // N (histogram counts)
    int* offsets  = cursor + N;                           // N+1
    int* blksum   = offsets + N + 1;                      // <=640
    int* blkoff   = blksum + 640;                         // <=640

    const int B = 256;
    const int nblkN = (N + B - 1) / B;   // 391 (<=512 for k_scan2)
    const int nblkG = (N + 3) / 4;

    k_init<<<nblkN, B, 0, stream>>>(cursor, N);

    // histogram + rank
    if ((E & 3) == 0) {
        int nt = E / 4;
        k_hist4<<<(nt + B - 1) / B, B, 0, stream>>>((const int4*)col, cursor, (int4*)rank, nt);
    } else {
        k_hist1<<<(E + B - 1) / B, B, 0, stream>>>(col, cursor, rank, E);
    }

    // scan counts -> offsets
    k_scan1<<<nblkN, B, 0, stream>>>(cursor, offsets, blksum, N);
    k_scan2<<<1, 512, 0, stream>>>(blksum, blkoff, nblkN);
    k_scan3<<<nblkN, B, 0, stream>>>(cursor, offsets, blkoff, N, E);

    // fill CSR (no atomics)
    if ((E & 3) == 0) {
        int nt = E / 4;
        k_fill4<<<(nt + B - 1) / B, B, 0, stream>>>((const int4*)row, (const int4*)col,
                                                    (const float4*)ew, (const int4*)rank,
                                                    offsets, sedge, nt);
    } else {
        k_fill1<<<(E + B - 1) / B, B, 0, stream>>>(row, col, ew, rank, offsets, sedge, E);
    }

    // dinv from segmented degree sum
    k_deg_seg<<<nblkG, B, 0, stream>>>(sedge, offsets, dinv, N);

    // layer 1
    k_mm<<<nblkG, B, 0, stream>>>(x, W1, xw, N);
    k_gather<<<nblkG, B, 0, stream>>>(xw, offsets, sedge, dinv, b1, x, temp, N);

    // layer 2
    k_mm<<<nblkG, B, 0, stream>>>(temp, W2, xw, N);
    k_gather<<<nblkG, B, 0, stream>>>(xw, offsets, sedge, dinv, b2, temp, (float*)d_out, N);
}

// Round 4
// 393.843 us; speedup vs baseline: 6.1374x; 1.0552x over previous
//
#include <hip/hip_runtime.h>

#define DIM 64
#define PRESERVE 0.1f

__device__ __forceinline__ float readlane_f(float v, int l) {
    return __int_as_float(__builtin_amdgcn_readlane(__float_as_int(v), l));
}

// ---------- init ----------
__global__ void k_init(int* cursor, int n) {
    int i = blockIdx.x * blockDim.x + threadIdx.x;
    if (i < n) cursor[i] = 0;
}

// ---------- histogram + rank (atomic return = rank in bucket) ----------
__global__ void k_hist4(const int4* __restrict__ col4, int* cursor,
                        int4* __restrict__ rank4, int nthreads) {
    int t = blockIdx.x * blockDim.x + threadIdx.x;
    if (t >= nthreads) return;
    int4 c = col4[t];
    int4 r;
    r.x = atomicAdd(&cursor[c.x], 1);
    r.y = atomicAdd(&cursor[c.y], 1);
    r.z = atomicAdd(&cursor[c.z], 1);
    r.w = atomicAdd(&cursor[c.w], 1);
    rank4[t] = r;
}

__global__ void k_hist1(const int* __restrict__ col, int* cursor,
                        int* __restrict__ rank, int E) {
    int e = blockIdx.x * blockDim.x + threadIdx.x;
    if (e < E) rank[e] = atomicAdd(&cursor[col[e]], 1);
}

// ---------- 2-level exclusive scan of counts(=cursor) -> offsets ----------
__global__ __launch_bounds__(256) void k_scan1(const int* __restrict__ counts,
                                               int* __restrict__ offsets,
                                               int* __restrict__ blksum, int n) {
    __shared__ int s[256];
    int t = threadIdx.x;
    int idx = blockIdx.x * 256 + t;
    int v = (idx < n) ? counts[idx] : 0;
    s[t] = v;
    __syncthreads();
    for (int off = 1; off < 256; off <<= 1) {
        int x = (t >= off) ? s[t - off] : 0;
        __syncthreads();
        s[t] += x;
        __syncthreads();
    }
    if (idx < n) offsets[idx] = s[t];
    if (t == 255) blksum[blockIdx.x] = s[255];
}

__global__ __launch_bounds__(512) void k_scan2(const int* __restrict__ blksum,
                                               int* __restrict__ blkoff, int nblk) {
    __shared__ int s[512];
    int t = threadIdx.x;
    int v = (t < nblk) ? blksum[t] : 0;
    s[t] = v;
    __syncthreads();
    for (int off = 1; off < 512; off <<= 1) {
        int x = (t >= off) ? s[t - off] : 0;
        __syncthreads();
        s[t] += x;
        __syncthreads();
    }
    if (t < nblk) blkoff[t] = s[t] - v;  // exclusive
}

__global__ __launch_bounds__(256) void k_scan3(const int* __restrict__ counts,
                                               int* __restrict__ offsets,
                                               const int* __restrict__ blkoff,
                                               int n, int E) {
    int t = threadIdx.x;
    int idx = blockIdx.x * 256 + t;
    if (idx < n) offsets[idx] = offsets[idx] - counts[idx] + blkoff[blockIdx.x];
    if (idx == 0) offsets[n] = E;
}

// ---------- bucket-fill CSR: sedge[offsets[col]+rank] = {row, w} ----------
__global__ void k_fill4(const int4* __restrict__ row4, const int4* __restrict__ col4,
                        const float4* __restrict__ w4, const int4* __restrict__ rank4,
                        const int* __restrict__ offsets, int2* __restrict__ sedge,
                        int nthreads) {
    int t = blockIdx.x * blockDim.x + threadIdx.x;
    if (t >= nthreads) return;
    int4 r = row4[t];
    int4 c = col4[t];
    float4 w = w4[t];
    int4 k = rank4[t];
    int2 p;
    p.x = r.x; p.y = __float_as_int(w.x); sedge[offsets[c.x] + k.x] = p;
    p.x = r.y; p.y = __float_as_int(w.y); sedge[offsets[c.y] + k.y] = p;
    p.x = r.z; p.y = __float_as_int(w.z); sedge[offsets[c.z] + k.z] = p;
    p.x = r.w; p.y = __float_as_int(w.w); sedge[offsets[c.w] + k.w] = p;
}

__global__ void k_fill1(const int* __restrict__ row, const int* __restrict__ col,
                        const float* __restrict__ w, const int* __restrict__ rank,
                        const int* __restrict__ offsets, int2* __restrict__ sedge,
                        int E) {
    int e = blockIdx.x * blockDim.x + threadIdx.x;
    if (e >= E) return;
    int2 p;
    p.x = row[e];
    p.y = __float_as_int(w[e]);
    sedge[offsets[col[e]] + rank[e]] = p;
}

// ---------- deg -> dinv from CSR (wave per node, no atomics) ----------
__global__ __launch_bounds__(256) void k_deg_seg(const int2* __restrict__ sedge,
                                                 const int* __restrict__ offsets,
                                                 float* __restrict__ dinv, int n) {
    int tid = threadIdx.x;
    int lane = tid & 63;
    int c = blockIdx.x * 4 + (tid >> 6);
    if (c >= n) return;
    int beg = offsets[c];
    int end = offsets[c + 1];
    float s = 0.0f;
    for (int j = beg + lane; j < end; j += 64) s += __int_as_float(sedge[j].y);
    for (int off = 32; off > 0; off >>= 1) s += __shfl_xor(s, off);
    if (lane == 0) {
        float d = 1.0f + s;  // self-loop weight
        dinv[c] = (d > 0.0f) ? rsqrtf(d) : 0.0f;
    }
}

// ---------- xs = (x @ W) * dinv[row]  (source norm folded into matmul) ----------
__global__ __launch_bounds__(256) void k_mm(
        const float* __restrict__ x, const float* __restrict__ W,
        const float* __restrict__ dinv, float* __restrict__ xs, int n) {
    __shared__ float Wl[DIM * DIM];
    __shared__ float xl[4 * DIM];
    int tid = threadIdx.x;
    for (int i = tid; i < DIM * DIM; i += 256) Wl[i] = W[i];
    int rowBase = blockIdx.x * 4;
    if (rowBase + (tid >> 6) < n) xl[tid] = x[rowBase * DIM + tid];
    __syncthreads();
    int sub = tid >> 6;
    int d = tid & 63;
    int r = rowBase + sub;
    if (r >= n) return;
    float t = 0.0f;
#pragma unroll
    for (int k = 0; k < DIM; ++k) t += xl[sub * DIM + k] * Wl[k * DIM + d];
    xs[(size_t)r * DIM + d] = t * dinv[r];
}

// ---------- gather (wave per node, lane = dim) ----------
// out[c] = 0.9*( dinv[c]*( xs[c] + sum_e w_e*xs[row_e] ) + b ) + 0.1*xprev[c]
__global__ __launch_bounds__(256) void k_gather(
        const float* __restrict__ xs, const int* __restrict__ offsets,
        const int2* __restrict__ sedge, const float* __restrict__ dinv,
        const float* __restrict__ b, const float* __restrict__ xprev,
        float* __restrict__ out, int n) {
    int tid = threadIdx.x;
    int lane = tid & 63;
    int c = blockIdx.x * 4 + (tid >> 6);
    if (c >= n) return;
    float di = dinv[c];
    float acc = xs[(size_t)c * DIM + lane];  // self-loop: xw[c]*di^2 = (xs[c])*di done at end
    int beg = offsets[c];
    int end = offsets[c + 1];
    for (int b0 = beg; b0 < end; b0 += 64) {
        int m = end - b0;
        if (m > 64) m = 64;
        int r_l = 0, w_l = 0;
        if (lane < m) {
            int2 p = sedge[b0 + lane];  // coalesced batch load; no dinv gather needed
            r_l = p.x;
            w_l = p.y;
        }
        int j = 0;
        for (; j + 3 < m; j += 4) {
            int r0 = __builtin_amdgcn_readlane(r_l, j);
            int r1 = __builtin_amdgcn_readlane(r_l, j + 1);
            int r2 = __builtin_amdgcn_readlane(r_l, j + 2);
            int r3 = __builtin_amdgcn_readlane(r_l, j + 3);
            float w0 = readlane_f(__int_as_float(w_l), j);
            float w1 = readlane_f(__int_as_float(w_l), j + 1);
            float w2 = readlane_f(__int_as_float(w_l), j + 2);
            float w3 = readlane_f(__int_as_float(w_l), j + 3);
            float a0 = xs[(size_t)r0 * DIM + lane];
            float a1 = xs[(size_t)r1 * DIM + lane];
            float a2 = xs[(size_t)r2 * DIM + lane];
            float a3 = xs[(size_t)r3 * DIM + lane];
            acc += a0 * w0;
            acc += a1 * w1;
            acc += a2 * w2;
            acc += a3 * w3;
        }
        for (; j < m; ++j) {
            int r0 = __builtin_amdgcn_readlane(r_l, j);
            float w0 = readlane_f(__int_as_float(w_l), j);
            acc += xs[(size_t)r0 * DIM + lane] * w0;
        }
    }
    float v = (1.0f - PRESERVE) * (acc * di + b[lane]) + PRESERVE * xprev[(size_t)c * DIM + lane];
    out[(size_t)c * DIM + lane] = v;
}

extern "C" void kernel_launch(void* const* d_in, const int* in_sizes, int n_in,
                              void* d_out, int out_size, void* d_ws, size_t ws_size,
                              hipStream_t stream) {
    const float* x  = (const float*)d_in[0];
    const int*   ei = (const int*)d_in[1];
    const float* ew = (const float*)d_in[2];
    const float* W1 = (const float*)d_in[3];
    const float* b1 = (const float*)d_in[4];
    const float* W2 = (const float*)d_in[5];
    const float* b2 = (const float*)d_in[6];

    const int N = in_sizes[0] / DIM;      // 100000
    const int E = in_sizes[2];            // 1250000
    const int* row = ei;
    const int* col = ei + E;

    // workspace layout (sedge first for 8B alignment)
    int2* sedge   = (int2*)d_ws;                          // E
    float* dinv   = (float*)(sedge + E);                  // N
    float* xs     = dinv + N;                             // N*DIM
    float* temp   = xs + (size_t)N * DIM;                 // N*DIM
    int* rank     = (int*)(temp + (size_t)N * DIM);       // E
    int* cursor   = rank + E;                             // N (histogram counts)
    int* offsets  = cursor + N;                           // N+1
    int* blksum   = offsets + N + 1;                      // <=640
    int* blkoff   = blksum + 640;                         // <=640

    const int B = 256;
    const int nblkN = (N + B - 1) / B;   // 391 (<=512 for k_scan2)
    const int nblkG = (N + 3) / 4;

    k_init<<<nblkN, B, 0, stream>>>(cursor, N);

    // histogram + rank
    if ((E & 3) == 0) {
        int nt = E / 4;
        k_hist4<<<(nt + B - 1) / B, B, 0, stream>>>((const int4*)col, cursor, (int4*)rank, nt);
    } else {
        k_hist1<<<(E + B - 1) / B, B, 0, stream>>>(col, cursor, rank, E);
    }

    // scan counts -> offsets
    k_scan1<<<nblkN, B, 0, stream>>>(cursor, offsets, blksum, N);
    k_scan2<<<1, 512, 0, stream>>>(blksum, blkoff, nblkN);
    k_scan3<<<nblkN, B, 0, stream>>>(cursor, offsets, blkoff, N, E);

    // fill CSR (no atomics)
    if ((E & 3) == 0) {
        int nt = E / 4;
        k_fill4<<<(nt + B - 1) / B, B, 0, stream>>>((const int4*)row, (const int4*)col,
                                                    (const float4*)ew, (const int4*)rank,
                                                    offsets, sedge, nt);
    } else {
        k_fill1<<<(E + B - 1) / B, B, 0, stream>>>(row, col, ew, rank, offsets, sedge, E);
    }

    // dinv from segmented degree sum
    k_deg_seg<<<nblkG, B, 0, stream>>>(sedge, offsets, dinv, N);

    // layer 1
    k_mm<<<nblkG, B, 0, stream>>>(x, W1, dinv, xs, N);
    k_gather<<<nblkG, B, 0, stream>>>(xs, offsets, sedge, dinv, b1, x, temp, N);

    // layer 2
    k_mm<<<nblkG, B, 0, stream>>>(temp, W2, dinv, xs, N);
    k_gather<<<nblkG, B, 0, stream>>>(xs, offsets, sedge, dinv, b2, temp, (float*)d_out, N);
}

// Round 5
// 351.722 us; speedup vs baseline: 6.8724x; 1.1198x over previous
//
#include <hip/hip_runtime.h>

#define DIM 64
#define PRESERVE 0.1f

__device__ __forceinline__ float readlane_f(float v, int l) {
    return __int_as_float(__builtin_amdgcn_readlane(__float_as_int(v), l));
}

// ---------- init ----------
__global__ void k_init(int* cursor, int n) {
    int i = blockIdx.x * blockDim.x + threadIdx.x;
    if (i < n) cursor[i] = 0;
}

// ---------- histogram + rank (atomic return = rank in bucket) ----------
__global__ void k_hist4(const int4* __restrict__ col4, int* cursor,
                        int4* __restrict__ rank4, int nthreads) {
    int t = blockIdx.x * blockDim.x + threadIdx.x;
    if (t >= nthreads) return;
    int4 c = col4[t];
    int4 r;
    r.x = atomicAdd(&cursor[c.x], 1);
    r.y = atomicAdd(&cursor[c.y], 1);
    r.z = atomicAdd(&cursor[c.z], 1);
    r.w = atomicAdd(&cursor[c.w], 1);
    rank4[t] = r;
}

__global__ void k_hist1(const int* __restrict__ col, int* cursor,
                        int* __restrict__ rank, int E) {
    int e = blockIdx.x * blockDim.x + threadIdx.x;
    if (e < E) rank[e] = atomicAdd(&cursor[col[e]], 1);
}

// ---------- 2-level exclusive scan of counts(=cursor) -> offsets ----------
__global__ __launch_bounds__(256) void k_scan1(const int* __restrict__ counts,
                                               int* __restrict__ offsets,
                                               int* __restrict__ blksum, int n) {
    __shared__ int s[256];
    int t = threadIdx.x;
    int idx = blockIdx.x * 256 + t;
    int v = (idx < n) ? counts[idx] : 0;
    s[t] = v;
    __syncthreads();
    for (int off = 1; off < 256; off <<= 1) {
        int x = (t >= off) ? s[t - off] : 0;
        __syncthreads();
        s[t] += x;
        __syncthreads();
    }
    if (idx < n) offsets[idx] = s[t];
    if (t == 255) blksum[blockIdx.x] = s[255];
}

__global__ __launch_bounds__(512) void k_scan2(const int* __restrict__ blksum,
                                               int* __restrict__ blkoff, int nblk) {
    __shared__ int s[512];
    int t = threadIdx.x;
    int v = (t < nblk) ? blksum[t] : 0;
    s[t] = v;
    __syncthreads();
    for (int off = 1; off < 512; off <<= 1) {
        int x = (t >= off) ? s[t - off] : 0;
        __syncthreads();
        s[t] += x;
        __syncthreads();
    }
    if (t < nblk) blkoff[t] = s[t] - v;  // exclusive
}

__global__ __launch_bounds__(256) void k_scan3(const int* __restrict__ counts,
                                               int* __restrict__ offsets,
                                               const int* __restrict__ blkoff,
                                               int n, int E) {
    int t = threadIdx.x;
    int idx = blockIdx.x * 256 + t;
    if (idx < n) offsets[idx] = offsets[idx] - counts[idx] + blkoff[blockIdx.x];
    if (idx == 0) offsets[n] = E;
}

// ---------- bucket-fill CSR: sedge[offsets[col]+rank] = {row, w} ----------
__global__ void k_fill4(const int4* __restrict__ row4, const int4* __restrict__ col4,
                        const float4* __restrict__ w4, const int4* __restrict__ rank4,
                        const int* __restrict__ offsets, int2* __restrict__ sedge,
                        int nthreads) {
    int t = blockIdx.x * blockDim.x + threadIdx.x;
    if (t >= nthreads) return;
    int4 r = row4[t];
    int4 c = col4[t];
    float4 w = w4[t];
    int4 k = rank4[t];
    int2 p;
    p.x = r.x; p.y = __float_as_int(w.x); sedge[offsets[c.x] + k.x] = p;
    p.x = r.y; p.y = __float_as_int(w.y); sedge[offsets[c.y] + k.y] = p;
    p.x = r.z; p.y = __float_as_int(w.z); sedge[offsets[c.z] + k.z] = p;
    p.x = r.w; p.y = __float_as_int(w.w); sedge[offsets[c.w] + k.w] = p;
}

__global__ void k_fill1(const int* __restrict__ row, const int* __restrict__ col,
                        const float* __restrict__ w, const int* __restrict__ rank,
                        const int* __restrict__ offsets, int2* __restrict__ sedge,
                        int E) {
    int e = blockIdx.x * blockDim.x + threadIdx.x;
    if (e >= E) return;
    int2 p;
    p.x = row[e];
    p.y = __float_as_int(w[e]);
    sedge[offsets[col[e]] + rank[e]] = p;
}

// ---------- deg -> dinv from CSR (wave per node, no atomics) ----------
__global__ __launch_bounds__(256) void k_deg_seg(const int2* __restrict__ sedge,
                                                 const int* __restrict__ offsets,
                                                 float* __restrict__ dinv, int n) {
    int tid = threadIdx.x;
    int lane = tid & 63;
    int c = blockIdx.x * 4 + (tid >> 6);
    if (c >= n) return;
    int beg = offsets[c];
    int end = offsets[c + 1];
    float s = 0.0f;
    for (int j = beg + lane; j < end; j += 64) s += __int_as_float(sedge[j].y);
    for (int off = 32; off > 0; off >>= 1) s += __shfl_xor(s, off);
    if (lane == 0) {
        float d = 1.0f + s;  // self-loop weight
        dinv[c] = (d > 0.0f) ? rsqrtf(d) : 0.0f;
    }
}

// ---------- xs = (x @ W) * dinv[row] ----------
// Zero-LDS: lane d holds W[:,d] in 64 VGPRs; x broadcast via v_readlane.
// Grid-stride, 4 rows per wave-iteration (4 independent acc chains).
__global__ __launch_bounds__(256) void k_mm(
        const float* __restrict__ x, const float* __restrict__ W,
        const float* __restrict__ dinv, float* __restrict__ xs, int n) {
    int tid = threadIdx.x;
    int lane = tid & 63;
    int waveId = blockIdx.x * 4 + (tid >> 6);
    int nWaves = gridDim.x * 4;

    float Wr[DIM];
#pragma unroll
    for (int k = 0; k < DIM; ++k) Wr[k] = W[k * DIM + lane];

    for (int r0 = waveId * 4; r0 < n; r0 += nWaves * 4) {
        if (r0 + 3 < n) {
            float x0 = x[(size_t)(r0 + 0) * DIM + lane];
            float x1 = x[(size_t)(r0 + 1) * DIM + lane];
            float x2 = x[(size_t)(r0 + 2) * DIM + lane];
            float x3 = x[(size_t)(r0 + 3) * DIM + lane];
            float a0 = 0.f, a1 = 0.f, a2 = 0.f, a3 = 0.f;
#pragma unroll
            for (int k = 0; k < DIM; ++k) {
                float w = Wr[k];
                a0 += readlane_f(x0, k) * w;
                a1 += readlane_f(x1, k) * w;
                a2 += readlane_f(x2, k) * w;
                a3 += readlane_f(x3, k) * w;
            }
            xs[(size_t)(r0 + 0) * DIM + lane] = a0 * dinv[r0 + 0];
            xs[(size_t)(r0 + 1) * DIM + lane] = a1 * dinv[r0 + 1];
            xs[(size_t)(r0 + 2) * DIM + lane] = a2 * dinv[r0 + 2];
            xs[(size_t)(r0 + 3) * DIM + lane] = a3 * dinv[r0 + 3];
        } else {
            for (int r = r0; r < n; ++r) {
                float xv = x[(size_t)r * DIM + lane];
                float a = 0.f;
#pragma unroll
                for (int k = 0; k < DIM; ++k) a += readlane_f(xv, k) * Wr[k];
                xs[(size_t)r * DIM + lane] = a * dinv[r];
            }
        }
    }
}

// ---------- gather (wave per node, lane = dim) ----------
// out[c] = 0.9*( dinv[c]*( xs[c] + sum_e w_e*xs[row_e] ) + b ) + 0.1*xprev[c]
__global__ __launch_bounds__(256) void k_gather(
        const float* __restrict__ xs, const int* __restrict__ offsets,
        const int2* __restrict__ sedge, const float* __restrict__ dinv,
        const float* __restrict__ b, const float* __restrict__ xprev,
        float* __restrict__ out, int n) {
    int tid = threadIdx.x;
    int lane = tid & 63;
    int c = blockIdx.x * 4 + (tid >> 6);
    if (c >= n) return;
    float di = dinv[c];
    float acc = xs[(size_t)c * DIM + lane];
    int beg = offsets[c];
    int end = offsets[c + 1];
    for (int b0 = beg; b0 < end; b0 += 64) {
        int m = end - b0;
        if (m > 64) m = 64;
        int r_l = 0, w_l = 0;
        if (lane < m) {
            int2 p = sedge[b0 + lane];  // coalesced batch load
            r_l = p.x;
            w_l = p.y;
        }
        int j = 0;
        for (; j + 3 < m; j += 4) {
            int r0 = __builtin_amdgcn_readlane(r_l, j);
            int r1 = __builtin_amdgcn_readlane(r_l, j + 1);
            int r2 = __builtin_amdgcn_readlane(r_l, j + 2);
            int r3 = __builtin_amdgcn_readlane(r_l, j + 3);
            float w0 = readlane_f(__int_as_float(w_l), j);
            float w1 = readlane_f(__int_as_float(w_l), j + 1);
            float w2 = readlane_f(__int_as_float(w_l), j + 2);
            float w3 = readlane_f(__int_as_float(w_l), j + 3);
            float a0 = xs[(size_t)r0 * DIM + lane];
            float a1 = xs[(size_t)r1 * DIM + lane];
            float a2 = xs[(size_t)r2 * DIM + lane];
            float a3 = xs[(size_t)r3 * DIM + lane];
            acc += a0 * w0;
            acc += a1 * w1;
            acc += a2 * w2;
            acc += a3 * w3;
        }
        for (; j < m; ++j) {
            int r0 = __builtin_amdgcn_readlane(r_l, j);
            float w0 = readlane_f(__int_as_float(w_l), j);
            acc += xs[(size_t)r0 * DIM + lane] * w0;
        }
    }
    float v = (1.0f - PRESERVE) * (acc * di + b[lane]) + PRESERVE * xprev[(size_t)c * DIM + lane];
    out[(size_t)c * DIM + lane] = v;
}

extern "C" void kernel_launch(void* const* d_in, const int* in_sizes, int n_in,
                              void* d_out, int out_size, void* d_ws, size_t ws_size,
                              hipStream_t stream) {
    const float* x  = (const float*)d_in[0];
    const int*   ei = (const int*)d_in[1];
    const float* ew = (const float*)d_in[2];
    const float* W1 = (const float*)d_in[3];
    const float* b1 = (const float*)d_in[4];
    const float* W2 = (const float*)d_in[5];
    const float* b2 = (const float*)d_in[6];

    const int N = in_sizes[0] / DIM;      // 100000
    const int E = in_sizes[2];            // 1250000
    const int* row = ei;
    const int* col = ei + E;

    // workspace layout (sedge first for 8B alignment)
    int2* sedge   = (int2*)d_ws;                          // E
    float* dinv   = (float*)(sedge + E);                  // N
    float* xs     = dinv + N;                             // N*DIM
    float* temp   = xs + (size_t)N * DIM;                 // N*DIM
    int* rank     = (int*)(temp + (size_t)N * DIM);       // E
    int* cursor   = rank + E;                             // N (histogram counts)
    int* offsets  = cursor + N;                           // N+1
    int* blksum   = offsets + N + 1;                      // <=640
    int* blkoff   = blksum + 640;                         // <=640

    const int B = 256;
    const int nblkN = (N + B - 1) / B;   // 391 (<=512 for k_scan2)
    const int nblkG = (N + 3) / 4;
    const int nblkMM = 1024;             // grid-stride; 4096 waves

    k_init<<<nblkN, B, 0, stream>>>(cursor, N);

    // histogram + rank
    if ((E & 3) == 0) {
        int nt = E / 4;
        k_hist4<<<(nt + B - 1) / B, B, 0, stream>>>((const int4*)col, cursor, (int4*)rank, nt);
    } else {
        k_hist1<<<(E + B - 1) / B, B, 0, stream>>>(col, cursor, rank, E);
    }

    // scan counts -> offsets
    k_scan1<<<nblkN, B, 0, stream>>>(cursor, offsets, blksum, N);
    k_scan2<<<1, 512, 0, stream>>>(blksum, blkoff, nblkN);
    k_scan3<<<nblkN, B, 0, stream>>>(cursor, offsets, blkoff, N, E);

    // fill CSR (no atomics)
    if ((E & 3) == 0) {
        int nt = E / 4;
        k_fill4<<<(nt + B - 1) / B, B, 0, stream>>>((const int4*)row, (const int4*)col,
                                                    (const float4*)ew, (const int4*)rank,
                                                    offsets, sedge, nt);
    } else {
        k_fill1<<<(E + B - 1) / B, B, 0, stream>>>(row, col, ew, rank, offsets, sedge, E);
    }

    // dinv from segmented degree sum
    k_deg_seg<<<nblkG, B, 0, stream>>>(sedge, offsets, dinv, N);

    // layer 1
    k_mm<<<nblkMM, B, 0, stream>>>(x, W1, dinv, xs, N);
    k_gather<<<nblkG, B, 0, stream>>>(xs, offsets, sedge, dinv, b1, x, temp, N);

    // layer 2
    k_mm<<<nblkMM, B, 0, stream>>>(temp, W2, dinv, xs, N);
    k_gather<<<nblkG, B, 0, stream>>>(xs, offsets, sedge, dinv, b2, temp, (float*)d_out, N);
}

// Round 6
// 333.044 us; speedup vs baseline: 7.2578x; 1.0561x over previous
//
#include <hip/hip_runtime.h>

#define DIM 64
#define PRESERVE 0.1f

typedef unsigned short bf16_t;

__device__ __forceinline__ float readlane_f(float v, int l) {
    return __int_as_float(__builtin_amdgcn_readlane(__float_as_int(v), l));
}
__device__ __forceinline__ float bf2f(bf16_t u) {
    return __uint_as_float(((unsigned)u) << 16);
}
__device__ __forceinline__ bf16_t f2bf(float f) {
    unsigned u = __float_as_uint(f);
    unsigned r = (u + 0x7FFFu + ((u >> 16) & 1u)) >> 16;  // RNE
    return (bf16_t)r;
}

// ---------- init ----------
__global__ void k_init(int* cursor, int n) {
    int i = blockIdx.x * blockDim.x + threadIdx.x;
    if (i < n) cursor[i] = 0;
}

// ---------- histogram + rank (atomic return = rank in bucket) ----------
__global__ void k_hist4(const int4* __restrict__ col4, int* cursor,
                        int4* __restrict__ rank4, int nthreads) {
    int t = blockIdx.x * blockDim.x + threadIdx.x;
    if (t >= nthreads) return;
    int4 c = col4[t];
    int4 r;
    r.x = atomicAdd(&cursor[c.x], 1);
    r.y = atomicAdd(&cursor[c.y], 1);
    r.z = atomicAdd(&cursor[c.z], 1);
    r.w = atomicAdd(&cursor[c.w], 1);
    rank4[t] = r;
}

__global__ void k_hist1(const int* __restrict__ col, int* cursor,
                        int* __restrict__ rank, int E) {
    int e = blockIdx.x * blockDim.x + threadIdx.x;
    if (e < E) rank[e] = atomicAdd(&cursor[col[e]], 1);
}

// ---------- 2-level exclusive scan of counts(=cursor) -> offsets ----------
__global__ __launch_bounds__(256) void k_scan1(const int* __restrict__ counts,
                                               int* __restrict__ offsets,
                                               int* __restrict__ blksum, int n) {
    __shared__ int s[256];
    int t = threadIdx.x;
    int idx = blockIdx.x * 256 + t;
    int v = (idx < n) ? counts[idx] : 0;
    s[t] = v;
    __syncthreads();
    for (int off = 1; off < 256; off <<= 1) {
        int x = (t >= off) ? s[t - off] : 0;
        __syncthreads();
        s[t] += x;
        __syncthreads();
    }
    if (idx < n) offsets[idx] = s[t];
    if (t == 255) blksum[blockIdx.x] = s[255];
}

__global__ __launch_bounds__(512) void k_scan2(const int* __restrict__ blksum,
                                               int* __restrict__ blkoff, int nblk) {
    __shared__ int s[512];
    int t = threadIdx.x;
    int v = (t < nblk) ? blksum[t] : 0;
    s[t] = v;
    __syncthreads();
    for (int off = 1; off < 512; off <<= 1) {
        int x = (t >= off) ? s[t - off] : 0;
        __syncthreads();
        s[t] += x;
        __syncthreads();
    }
    if (t < nblk) blkoff[t] = s[t] - v;  // exclusive
}

__global__ __launch_bounds__(256) void k_scan3(const int* __restrict__ counts,
                                               int* __restrict__ offsets,
                                               const int* __restrict__ blkoff,
                                               int n, int E) {
    int t = threadIdx.x;
    int idx = blockIdx.x * 256 + t;
    if (idx < n) offsets[idx] = offsets[idx] - counts[idx] + blkoff[blockIdx.x];
    if (idx == 0) offsets[n] = E;
}

// ---------- bucket-fill CSR: sedge[offsets[col]+rank] = {row, w} ----------
__global__ void k_fill4(const int4* __restrict__ row4, const int4* __restrict__ col4,
                        const float4* __restrict__ w4, const int4* __restrict__ rank4,
                        const int* __restrict__ offsets, int2* __restrict__ sedge,
                        int nthreads) {
    int t = blockIdx.x * blockDim.x + threadIdx.x;
    if (t >= nthreads) return;
    int4 r = row4[t];
    int4 c = col4[t];
    float4 w = w4[t];
    int4 k = rank4[t];
    int2 p;
    p.x = r.x; p.y = __float_as_int(w.x); sedge[offsets[c.x] + k.x] = p;
    p.x = r.y; p.y = __float_as_int(w.y); sedge[offsets[c.y] + k.y] = p;
    p.x = r.z; p.y = __float_as_int(w.z); sedge[offsets[c.z] + k.z] = p;
    p.x = r.w; p.y = __float_as_int(w.w); sedge[offsets[c.w] + k.w] = p;
}

__global__ void k_fill1(const int* __restrict__ row, const int* __restrict__ col,
                        const float* __restrict__ w, const int* __restrict__ rank,
                        const int* __restrict__ offsets, int2* __restrict__ sedge,
                        int E) {
    int e = blockIdx.x * blockDim.x + threadIdx.x;
    if (e >= E) return;
    int2 p;
    p.x = row[e];
    p.y = __float_as_int(w[e]);
    sedge[offsets[col[e]] + rank[e]] = p;
}

// ---------- deg -> dinv from CSR (wave per node, no atomics) ----------
__global__ __launch_bounds__(256) void k_deg_seg(const int2* __restrict__ sedge,
                                                 const int* __restrict__ offsets,
                                                 float* __restrict__ dinv, int n) {
    int tid = threadIdx.x;
    int lane = tid & 63;
    int c = blockIdx.x * 4 + (tid >> 6);
    if (c >= n) return;
    int beg = offsets[c];
    int end = offsets[c + 1];
    float s = 0.0f;
    for (int j = beg + lane; j < end; j += 64) s += __int_as_float(sedge[j].y);
    for (int off = 32; off > 0; off >>= 1) s += __shfl_xor(s, off);
    if (lane == 0) {
        float d = 1.0f + s;  // self-loop weight
        dinv[c] = (d > 0.0f) ? rsqrtf(d) : 0.0f;
    }
}

// ---------- xs = bf16( (x @ W) * dinv[row] ) ----------
// Zero-LDS: lane d holds W[:,d] in 64 VGPRs; x broadcast via v_readlane.
__global__ __launch_bounds__(256) void k_mm(
        const float* __restrict__ x, const float* __restrict__ W,
        const float* __restrict__ dinv, bf16_t* __restrict__ xs, int n) {
    int tid = threadIdx.x;
    int lane = tid & 63;
    int waveId = blockIdx.x * 4 + (tid >> 6);
    int nWaves = gridDim.x * 4;

    float Wr[DIM];
#pragma unroll
    for (int k = 0; k < DIM; ++k) Wr[k] = W[k * DIM + lane];

    for (int r0 = waveId * 4; r0 < n; r0 += nWaves * 4) {
        if (r0 + 3 < n) {
            float x0 = x[(size_t)(r0 + 0) * DIM + lane];
            float x1 = x[(size_t)(r0 + 1) * DIM + lane];
            float x2 = x[(size_t)(r0 + 2) * DIM + lane];
            float x3 = x[(size_t)(r0 + 3) * DIM + lane];
            float a0 = 0.f, a1 = 0.f, a2 = 0.f, a3 = 0.f;
#pragma unroll
            for (int k = 0; k < DIM; ++k) {
                float w = Wr[k];
                a0 += readlane_f(x0, k) * w;
                a1 += readlane_f(x1, k) * w;
                a2 += readlane_f(x2, k) * w;
                a3 += readlane_f(x3, k) * w;
            }
            xs[(size_t)(r0 + 0) * DIM + lane] = f2bf(a0 * dinv[r0 + 0]);
            xs[(size_t)(r0 + 1) * DIM + lane] = f2bf(a1 * dinv[r0 + 1]);
            xs[(size_t)(r0 + 2) * DIM + lane] = f2bf(a2 * dinv[r0 + 2]);
            xs[(size_t)(r0 + 3) * DIM + lane] = f2bf(a3 * dinv[r0 + 3]);
        } else {
            for (int r = r0; r < n; ++r) {
                float xv = x[(size_t)r * DIM + lane];
                float a = 0.f;
#pragma unroll
                for (int k = 0; k < DIM; ++k) a += readlane_f(xv, k) * Wr[k];
                xs[(size_t)r * DIM + lane] = f2bf(a * dinv[r]);
            }
        }
    }
}

// ---------- gather (wave per node, lane = dim), bf16 xs rows ----------
// out[c] = 0.9*( dinv[c]*( xs[c] + sum_e w_e*xs[row_e] ) + b ) + 0.1*xprev[c]
__global__ __launch_bounds__(256) void k_gather(
        const bf16_t* __restrict__ xs, const int* __restrict__ offsets,
        const int2* __restrict__ sedge, const float* __restrict__ dinv,
        const float* __restrict__ b, const float* __restrict__ xprev,
        float* __restrict__ out, int n) {
    int tid = threadIdx.x;
    int lane = tid & 63;
    int c = blockIdx.x * 4 + (tid >> 6);
    if (c >= n) return;
    float di = dinv[c];
    float acc = bf2f(xs[(size_t)c * DIM + lane]);
    int beg = offsets[c];
    int end = offsets[c + 1];
    for (int b0 = beg; b0 < end; b0 += 64) {
        int m = end - b0;
        if (m > 64) m = 64;
        int r_l = 0, w_l = 0;
        if (lane < m) {
            int2 p = sedge[b0 + lane];  // coalesced batch load
            r_l = p.x;
            w_l = p.y;
        }
        int j = 0;
        for (; j + 3 < m; j += 4) {
            int r0 = __builtin_amdgcn_readlane(r_l, j);
            int r1 = __builtin_amdgcn_readlane(r_l, j + 1);
            int r2 = __builtin_amdgcn_readlane(r_l, j + 2);
            int r3 = __builtin_amdgcn_readlane(r_l, j + 3);
            float w0 = readlane_f(__int_as_float(w_l), j);
            float w1 = readlane_f(__int_as_float(w_l), j + 1);
            float w2 = readlane_f(__int_as_float(w_l), j + 2);
            float w3 = readlane_f(__int_as_float(w_l), j + 3);
            float a0 = bf2f(xs[(size_t)r0 * DIM + lane]);
            float a1 = bf2f(xs[(size_t)r1 * DIM + lane]);
            float a2 = bf2f(xs[(size_t)r2 * DIM + lane]);
            float a3 = bf2f(xs[(size_t)r3 * DIM + lane]);
            acc += a0 * w0;
            acc += a1 * w1;
            acc += a2 * w2;
            acc += a3 * w3;
        }
        for (; j < m; ++j) {
            int r0 = __builtin_amdgcn_readlane(r_l, j);
            float w0 = readlane_f(__int_as_float(w_l), j);
            acc += bf2f(xs[(size_t)r0 * DIM + lane]) * w0;
        }
    }
    float v = (1.0f - PRESERVE) * (acc * di + b[lane]) + PRESERVE * xprev[(size_t)c * DIM + lane];
    out[(size_t)c * DIM + lane] = v;
}

extern "C" void kernel_launch(void* const* d_in, const int* in_sizes, int n_in,
                              void* d_out, int out_size, void* d_ws, size_t ws_size,
                              hipStream_t stream) {
    const float* x  = (const float*)d_in[0];
    const int*   ei = (const int*)d_in[1];
    const float* ew = (const float*)d_in[2];
    const float* W1 = (const float*)d_in[3];
    const float* b1 = (const float*)d_in[4];
    const float* W2 = (const float*)d_in[5];
    const float* b2 = (const float*)d_in[6];

    const int N = in_sizes[0] / DIM;      // 100000
    const int E = in_sizes[2];            // 1250000
    const int* row = ei;
    const int* col = ei + E;

    // workspace layout (sedge first for 8B alignment)
    int2* sedge   = (int2*)d_ws;                          // E
    float* dinv   = (float*)(sedge + E);                  // N
    float* temp   = dinv + N;                             // N*DIM fp32
    bf16_t* xs    = (bf16_t*)(temp + (size_t)N * DIM);    // N*DIM bf16
    int* rank     = (int*)(xs + (size_t)N * DIM);         // E
    int* cursor   = rank + E;                             // N (histogram counts)
    int* offsets  = cursor + N;                           // N+1
    int* blksum   = offsets + N + 1;                      // <=640
    int* blkoff   = blksum + 640;                         // <=640

    const int B = 256;
    const int nblkN = (N + B - 1) / B;   // 391 (<=512 for k_scan2)
    const int nblkG = (N + 3) / 4;
    const int nblkMM = 1024;             // grid-stride; 4096 waves

    k_init<<<nblkN, B, 0, stream>>>(cursor, N);

    // histogram + rank
    if ((E & 3) == 0) {
        int nt = E / 4;
        k_hist4<<<(nt + B - 1) / B, B, 0, stream>>>((const int4*)col, cursor, (int4*)rank, nt);
    } else {
        k_hist1<<<(E + B - 1) / B, B, 0, stream>>>(col, cursor, rank, E);
    }

    // scan counts -> offsets
    k_scan1<<<nblkN, B, 0, stream>>>(cursor, offsets, blksum, N);
    k_scan2<<<1, 512, 0, stream>>>(blksum, blkoff, nblkN);
    k_scan3<<<nblkN, B, 0, stream>>>(cursor, offsets, blkoff, N, E);

    // fill CSR (no atomics)
    if ((E & 3) == 0) {
        int nt = E / 4;
        k_fill4<<<(nt + B - 1) / B, B, 0, stream>>>((const int4*)row, (const int4*)col,
                                                    (const float4*)ew, (const int4*)rank,
                                                    offsets, sedge, nt);
    } else {
        k_fill1<<<(E + B - 1) / B, B, 0, stream>>>(row, col, ew, rank, offsets, sedge, E);
    }

    // dinv from segmented degree sum
    k_deg_seg<<<nblkG, B, 0, stream>>>(sedge, offsets, dinv, N);

    // layer 1
    k_mm<<<nblkMM, B, 0, stream>>>(x, W1, dinv, xs, N);
    k_gather<<<nblkG, B, 0, stream>>>(xs, offsets, sedge, dinv, b1, x, temp, N);

    // layer 2
    k_mm<<<nblkMM, B, 0, stream>>>(temp, W2, dinv, xs, N);
    k_gather<<<nblkG, B, 0, stream>>>(xs, offsets, sedge, dinv, b2, temp, (float*)d_out, N);
}